// Round 16
// baseline (120.589 us; speedup 1.0000x reference)
//
#include <hip/hip_runtime.h>
#include <hip/hip_bf16.h>

typedef __attribute__((ext_vector_type(4))) float f32x4;
typedef __attribute__((ext_vector_type(16))) float f32x16;
typedef __attribute__((ext_vector_type(8))) short bf16x8;
typedef __attribute__((ext_vector_type(2))) unsigned int u32x2;

#define T_SEQ 2048
#define C_DIM 1024
#define NH 16
#define DHD 64

__device__ __forceinline__ unsigned cvtpk_bf16(float lo, float hi) {
    unsigned r;
    asm("v_cvt_pk_bf16_f32 %0, %1, %2" : "=v"(r) : "v"(lo), "v"(hi));
    return r;
}

// hardware 2^x
__device__ __forceinline__ float exp2_hw(float x) {
    float r;
    asm("v_exp_f32 %0, %1" : "=v"(r) : "v"(x));
    return r;
}

// async global->LDS, 16B per lane. LDS dest = wave-uniform base; HW adds lane*16.
__device__ __forceinline__ void async_copy16(void* lds, const void* g) {
    __builtin_amdgcn_global_load_lds(
        (const __attribute__((address_space(1))) unsigned int*)(uintptr_t)g,
        (__attribute__((address_space(3))) unsigned int*)(unsigned int)(uintptr_t)lds,
        16, 0, 0);
}

// ---------------- fused fp32 -> bf16 convert (packed 8B stores) ----------------
__global__ __launch_bounds__(256) void cvt_all(const float* __restrict__ x,
                                               const float* __restrict__ Wq, const float* __restrict__ Wk,
                                               const float* __restrict__ Wv, const float* __restrict__ Wp,
                                               __hip_bfloat16* __restrict__ xb,
                                               __hip_bfloat16* __restrict__ wf,
                                               __hip_bfloat16* __restrict__ wpb) {
    int i = blockIdx.x * blockDim.x + threadIdx.x;   // float4 index
    const float* src; __hip_bfloat16* dst; int off;
    if (i < 1048576) { src = x; dst = xb; off = i; }
    else {
        int j = i - 1048576; int wi = j >> 18; off = j & 262143;
        switch (wi) {
            case 0:  src = Wq; dst = wf;           break;
            case 1:  src = Wk; dst = wf + 1048576; break;
            case 2:  src = Wv; dst = wf + 2097152; break;
            default: src = Wp; dst = wpb;          break;
        }
    }
    float4 v = *(const float4*)(src + (size_t)off * 4);
    union { __hip_bfloat16 h[4]; u32x2 u; } p;
    p.h[0] = __float2bfloat16(v.x); p.h[1] = __float2bfloat16(v.y);
    p.h[2] = __float2bfloat16(v.z); p.h[3] = __float2bfloat16(v.w);
    *(u32x2*)(dst + (size_t)off * 4) = p.u;
}

// ---------------- QKV GEMM: 128x384 tile, BK=64, 6-phase counted-vmcnt schedule, 256 blocks ----------------
__global__ __launch_bounds__(512) void gemm_qkv(const __hip_bfloat16* __restrict__ A,
                                                const __hip_bfloat16* __restrict__ Bw,
                                                const float* __restrict__ biasq,
                                                const float* __restrict__ biask,
                                                const float* __restrict__ biasv,
                                                __hip_bfloat16* __restrict__ oq,
                                                __hip_bfloat16* __restrict__ okk,
                                                __hip_bfloat16* __restrict__ ovt) {
    __shared__ __align__(16) char lds[131072]; // A: 2buf x 2half x 8KB @0; B: 2buf x 2half x 24KB @32768

    const int wg = ((int)blockIdx.x & 7) * 32 + ((int)blockIdx.x >> 3);
    const int m0 = (wg & 31) * 128;   // 32 m-tiles
    const int n0 = (wg >> 5) * 384;   // 8 n-tiles

    const int tid = threadIdx.x;
    const int w = tid >> 6, l = tid & 63;
    const int wr = w >> 2, wc = w & 3;      // wave grid 2M x 4N: 64 rows x 96 cols per wave
    const int lg = l >> 4, lr = l & 15;

    const int sr0 = tid >> 3;
    const int sc0 = (tid & 7) * 16;
    const int gc0 = sc0 ^ ((sr0 & 7) << 4);
    const size_t goff = (size_t)sr0 * 2048 + gc0;

    const char* Ag = (const char*)A + (size_t)m0 * 2048;
    const char* Bg = (const char*)Bw + (size_t)n0 * 2048;

    auto STAGE_A = [&](int buf, int half, int kt) {
        const char* g = Ag + (size_t)(half * 64) * 2048 + kt * 128 + goff;
        char* d = lds + (buf * 2 + half) * 8192 + w * 1024;
        async_copy16(d, g);
    };
    auto STAGE_B = [&](int buf, int half, int kt) {
        #pragma unroll
        for (int p = 0; p < 3; p++) {
            const char* g = Bg + (size_t)(half * 192 + p * 64) * 2048 + kt * 128 + goff;
            char* d = lds + 32768 + (buf * 2 + half) * 24576 + p * 8192 + w * 1024;
            async_copy16(d, g);
        }
    };

    const int sw = (lr & 7) << 4;
    auto LDA = [&](bf16x8* af, int buf) {
        const char* base = lds + (buf * 2 + wr) * 8192;
        #pragma unroll
        for (int m = 0; m < 4; m++) {
            const int r = m * 16 + lr;
            #pragma unroll
            for (int kk = 0; kk < 2; kk++)
                af[m * 2 + kk] = *(const bf16x8*)(base + r * 128 + ((kk * 64 + lg * 16) ^ sw));
        }
    };
    auto LDB = [&](bf16x8* bfv, int buf, int nq) {
        const char* base = lds + 32768 + (buf * 2 + (wc >> 1)) * 24576;
        #pragma unroll
        for (int n = 0; n < 2; n++) {
            const int r = (wc & 1) * 96 + (nq * 2 + n) * 16 + lr;
            #pragma unroll
            for (int kk = 0; kk < 2; kk++)
                bfv[n * 2 + kk] = *(const bf16x8*)(base + r * 128 + ((kk * 64 + lg * 16) ^ sw));
        }
    };

    f32x4 acc[4][6] = {};
    auto MF = [&](const bf16x8* af, const bf16x8* bfv, int nq) {
        #pragma unroll
        for (int m = 0; m < 4; m++)
            #pragma unroll
            for (int n = 0; n < 2; n++)
                #pragma unroll
                for (int kk = 0; kk < 2; kk++)
                    acc[m][nq * 2 + n] = __builtin_amdgcn_mfma_f32_16x16x32_bf16(
                        af[m * 2 + kk], bfv[n * 2 + kk], acc[m][nq * 2 + n], 0, 0, 0);
    };

#define PH_OPEN()  __builtin_amdgcn_sched_barrier(0); \
                   __builtin_amdgcn_s_barrier(); \
                   asm volatile("s_waitcnt lgkmcnt(0)" ::: "memory"); \
                   __builtin_amdgcn_sched_barrier(0); \
                   __builtin_amdgcn_s_setprio(1);
#define PH_CLOSE() __builtin_amdgcn_s_setprio(0); \
                   __builtin_amdgcn_sched_barrier(0); \
                   __builtin_amdgcn_s_barrier();
#define PH_CLOSE_VM2() __builtin_amdgcn_s_setprio(0); \
                   asm volatile("s_waitcnt vmcnt(2)" ::: "memory"); \
                   __builtin_amdgcn_sched_barrier(0); \
                   __builtin_amdgcn_s_barrier();
#define PH_CLOSE_VM5() __builtin_amdgcn_s_setprio(0); \
                   asm volatile("s_waitcnt vmcnt(5)" ::: "memory"); \
                   __builtin_amdgcn_sched_barrier(0); \
                   __builtin_amdgcn_s_barrier();

    bf16x8 af[8], bfA[4], bfB[4], bfC[4];

    STAGE_B(0, 0, 0); STAGE_B(0, 1, 0); STAGE_A(0, 0, 0); STAGE_A(0, 1, 0);
    STAGE_A(1, 0, 1); STAGE_A(1, 1, 1); STAGE_B(1, 0, 1);
    asm volatile("s_waitcnt vmcnt(5)" ::: "memory");
    __builtin_amdgcn_sched_barrier(0);
    __builtin_amdgcn_s_barrier();

    for (int it = 0; it < 8; ++it) {
        const int t1 = 2 * it + 1;
        const int c2 = (2 * it + 2 < 16) ? 2 * it + 2 : 14;
        const int c3 = (2 * it + 3 < 16) ? 2 * it + 3 : 15;
        const int b2 = c2 & 1, b3 = c3 & 1;

        LDA(af, 0); LDB(bfA, 0, 0);
        STAGE_B(1, 1, t1);
        PH_OPEN(); MF(af, bfA, 0); PH_CLOSE();
        LDB(bfB, 0, 1);
        STAGE_A(b2, 0, c2); STAGE_A(b2, 1, c2);
        PH_OPEN(); MF(af, bfB, 1); PH_CLOSE();
        LDB(bfC, 0, 2);
        PH_OPEN(); MF(af, bfC, 2); PH_CLOSE_VM2();

        LDA(af, 1); LDB(bfA, 1, 0);
        STAGE_B(b2, 0, c2);
        PH_OPEN(); MF(af, bfA, 0); PH_CLOSE();
        LDB(bfB, 1, 1);
        STAGE_B(b2, 1, c2); STAGE_A(b3, 0, c3); STAGE_A(b3, 1, c3);
        PH_OPEN(); MF(af, bfB, 1); PH_CLOSE();
        LDB(bfC, 1, 2);
        STAGE_B(b3, 0, c3);
        PH_OPEN(); MF(af, bfC, 2); PH_CLOSE_VM5();
    }
#undef PH_OPEN
#undef PH_CLOSE
#undef PH_CLOSE_VM2
#undef PH_CLOSE_VM5

    #pragma unroll
    for (int m = 0; m < 4; m++) {
        const int rowb = m0 + wr * 64 + m * 16 + lg * 4;
        const int b = rowb >> 11, t0r = rowb & 2047;
        #pragma unroll
        for (int nf = 0; nf < 6; nf++) {
            const int col = n0 + wc * 96 + nf * 16 + lr;
            const int proj = col >> 10;
            const int colL = col & 1023;
            const int hh = colL >> 6, dd = colL & 63;
            if (proj < 2) {
                const float* bias = (proj == 0) ? biasq : biask;
                const float bsc = (proj == 0) ? 0.125f * 1.4426950408889634f : 1.0f;
                __hip_bfloat16* dst = (proj == 0) ? oq : okk;
                #pragma unroll
                for (int rr = 0; rr < 4; rr++) {
                    const int row = rowb + rr;
                    float val = (acc[m][nf][rr] + bias[colL]) * bsc;
                    dst[(((size_t)(b * NH + hh)) * T_SEQ + (row & 2047)) * DHD + dd] = __float2bfloat16(val);
                }
            } else {
                const float bv = biasv[colL];
                union { __hip_bfloat16 h[4]; u32x2 u; } p;
                #pragma unroll
                for (int rr = 0; rr < 4; rr++)
                    p.h[rr] = __float2bfloat16(acc[m][nf][rr] + bv);
                *(u32x2*)&ovt[(((size_t)(b * NH + hh)) * DHD + dd) * T_SEQ + t0r] = p.u;
            }
        }
    }
}

// ---------------- proj GEMM v2: 128x128 tile, BK=64, 4-phase counted-vmcnt, 256 blocks ----------------
__global__ __launch_bounds__(512) void gemm_proj2(const __hip_bfloat16* __restrict__ A,
                                                  const __hip_bfloat16* __restrict__ Bw,
                                                  const float* __restrict__ biasp,
                                                  float* __restrict__ outf) {
    __shared__ __align__(16) char lds[65536]; // A: 2buf x 2half x 8KB @0; B same @32768

    const int wg = ((int)blockIdx.x & 7) * 32 + ((int)blockIdx.x >> 3); // bijective, 256%8==0
    const int m0 = (wg & 31) * 128;
    const int n0 = (wg >> 5) * 128;

    const int tid = threadIdx.x;
    const int w = tid >> 6, l = tid & 63;
    const int wr = w >> 2, wc = w & 3;
    const int lg = l >> 4, lr = l & 15;

    const int sr0 = tid >> 3;
    const int sc0 = (tid & 7) * 16;
    const int gc0 = sc0 ^ ((sr0 & 7) << 4);
    const size_t goff = (size_t)sr0 * 2048 + gc0;

    const char* Ag = (const char*)A + (size_t)m0 * 2048;
    const char* Bg = (const char*)Bw + (size_t)n0 * 2048;

    auto STAGE_A = [&](int buf, int half, int kt) {
        const char* g = Ag + (size_t)(half * 64) * 2048 + kt * 128 + goff;
        char* d = lds + (buf * 2 + half) * 8192 + w * 1024;
        async_copy16(d, g);
    };
    auto STAGE_B = [&](int buf, int half, int kt) {
        const char* g = Bg + (size_t)(half * 64) * 2048 + kt * 128 + goff;
        char* d = lds + 32768 + (buf * 2 + half) * 8192 + w * 1024;
        async_copy16(d, g);
    };

    const int sw = (lr & 7) << 4;
    auto LDA = [&](bf16x8* af, int buf) {
        const char* base = lds + (buf * 2 + wr) * 8192;
        #pragma unroll
        for (int m = 0; m < 4; m++) {
            const int r = m * 16 + lr;
            #pragma unroll
            for (int kk = 0; kk < 2; kk++)
                af[m * 2 + kk] = *(const bf16x8*)(base + r * 128 + ((kk * 64 + lg * 16) ^ sw));
        }
    };
    auto LDB = [&](bf16x8* bfv, int buf, int n) {
        const char* base = lds + 32768 + (buf * 2 + (wc >> 1)) * 8192;
        const int r = (wc & 1) * 32 + n * 16 + lr;
        #pragma unroll
        for (int kk = 0; kk < 2; kk++)
            bfv[kk] = *(const bf16x8*)(base + r * 128 + ((kk * 64 + lg * 16) ^ sw));
    };

    f32x4 acc[4][2] = {};
    auto MF = [&](const bf16x8* af, const bf16x8* bfv, int n) {
        #pragma unroll
        for (int m = 0; m < 4; m++)
            #pragma unroll
            for (int kk = 0; kk < 2; kk++)
                acc[m][n] = __builtin_amdgcn_mfma_f32_16x16x32_bf16(
                    af[m * 2 + kk], bfv[kk], acc[m][n], 0, 0, 0);
    };

#define PH_OPEN()  __builtin_amdgcn_sched_barrier(0); \
                   __builtin_amdgcn_s_barrier(); \
                   asm volatile("s_waitcnt lgkmcnt(0)" ::: "memory"); \
                   __builtin_amdgcn_sched_barrier(0); \
                   __builtin_amdgcn_s_setprio(1);
#define PH_CLOSE() __builtin_amdgcn_s_setprio(0); \
                   __builtin_amdgcn_sched_barrier(0); \
                   __builtin_amdgcn_s_barrier();
#define PH_CLOSE_VM2() __builtin_amdgcn_s_setprio(0); \
                   asm volatile("s_waitcnt vmcnt(2)" ::: "memory"); \
                   __builtin_amdgcn_sched_barrier(0); \
                   __builtin_amdgcn_s_barrier();

    bf16x8 af[8], bf0[2], bf1[2];

    STAGE_B(0, 0, 0); STAGE_B(0, 1, 0); STAGE_A(0, 0, 0); STAGE_A(0, 1, 0);
    STAGE_A(1, 0, 1); STAGE_A(1, 1, 1);
    asm volatile("s_waitcnt vmcnt(2)" ::: "memory");
    __builtin_amdgcn_sched_barrier(0);
    __builtin_amdgcn_s_barrier();

    for (int it = 0; it < 8; ++it) {
        const int t1 = 2 * it + 1;
        const int c2 = (2 * it + 2 < 16) ? 2 * it + 2 : 14;
        const int c3 = (2 * it + 3 < 16) ? 2 * it + 3 : 15;
        const int b2 = c2 & 1, b3 = c3 & 1;

        LDA(af, 0); LDB(bf0, 0, 0);
        STAGE_B(1, 0, t1); STAGE_B(1, 1, t1);
        PH_OPEN(); MF(af, bf0, 0); PH_CLOSE();
        LDB(bf1, 0, 1);
        STAGE_A(b2, 0, c2); STAGE_A(b2, 1, c2);
        PH_OPEN(); MF(af, bf1, 1); PH_CLOSE_VM2();

        LDA(af, 1); LDB(bf0, 1, 0);
        STAGE_B(b2, 0, c2); STAGE_B(b2, 1, c2);
        PH_OPEN(); MF(af, bf0, 0); PH_CLOSE();
        LDB(bf1, 1, 1);
        STAGE_A(b3, 0, c3); STAGE_A(b3, 1, c3);
        PH_OPEN(); MF(af, bf1, 1); PH_CLOSE_VM2();
    }
#undef PH_OPEN
#undef PH_CLOSE
#undef PH_CLOSE_VM2

    #pragma unroll
    for (int m = 0; m < 4; m++)
        #pragma unroll
        for (int n = 0; n < 2; n++)
            #pragma unroll
            for (int r = 0; r < 4; r++) {
                int row = m0 + wr * 64 + m * 16 + lg * 4 + r;
                int col = n0 + wc * 32 + n * 16 + lr;
                outf[(size_t)row * C_DIM + col] = acc[m][n][r] + biasp[col];
            }
}

// ---------------- flash attention v11: attn8 per-wave math, 2 tiles per barrier (4-buffer pairs) ----------------
// Pair p reads tiles 2p,2p+1 from bufs {base,base+1} (base=(p&1)*2); writes tiles 2p+2,2p+3 into
// bufs {base^2,(base^2)+1} (last read pair p-1, barrier-separated). Barriers 32 -> 16.
__global__ __launch_bounds__(256) void attn11(const __hip_bfloat16* __restrict__ Q,
                                              const __hip_bfloat16* __restrict__ K,
                                              const __hip_bfloat16* __restrict__ Vt,
                                              __hip_bfloat16* __restrict__ Y) {
    const int bid = blockIdx.x;
    const int xcd = bid & 7, slot = bid >> 3;
    const int head = xcd * 4 + (slot & 3);
    const int qblk = slot >> 2;

    const int tid = threadIdx.x;
    const int w = tid >> 6, l = tid & 63;
    const int lq = l & 31, hi = l >> 5;
    const int q0 = qblk * 128 + w * 32;

    __shared__ __align__(16) char Ks[4][8192];
    __shared__ __align__(16) char Vs[4][8192];
    __shared__ float bc[4][32];

    const char* Kb = (const char*)(K + (size_t)head * T_SEQ * DHD);
    const char* Vb = (const char*)(Vt + (size_t)head * DHD * T_SEQ);

    bf16x8 qf[4];
    {
        const char* qrow = (const char*)(Q + ((size_t)head * T_SEQ + q0 + lq) * DHD);
        #pragma unroll
        for (int t = 0; t < 4; t++) qf[t] = *(const bf16x8*)(qrow + t * 32 + hi * 16);
    }

    f32x16 yacc[2] = {};
    float ls0 = 0.f, ls1 = 0.f, ls2 = 0.f, ls3 = 0.f;

    const int o0 = (2 * w) * 1024 + l * 16;
    const int o1 = o0 + 1024;
    const int r0 = o0 >> 7, c0b = o0 & 127;
    const int r1 = o1 >> 7, c1b = o1 & 127;
    const int wads0 = r0 * 128 + (c0b ^ ((r0 & 7) << 4));
    const int wads1 = r1 * 128 + (c1b ^ ((r1 & 7) << 4));
    const char* vsrc0 = Vb + (size_t)r0 * (T_SEQ * 2) + c0b;
    const char* vsrc1 = Vb + (size_t)r1 * (T_SEQ * 2) + c1b;

    // two tiles in flight: set A (even tile), set B (odd tile)
    float4 kA0, kA1, vA0, vA1, kB0, kB1, vB0, vB1;
    auto load_pair = [&](int tile) {               // loads tiles tile, tile+1
        const char* ka = Kb + (size_t)tile * 8192;
        const char* kb = ka + 8192;
        kA0 = *(const float4*)(ka + o0);  kA1 = *(const float4*)(ka + o1);
        kB0 = *(const float4*)(kb + o0);  kB1 = *(const float4*)(kb + o1);
        vA0 = *(const float4*)(vsrc0 + (size_t)tile * 128);
        vA1 = *(const float4*)(vsrc1 + (size_t)tile * 128);
        vB0 = *(const float4*)(vsrc0 + (size_t)(tile + 1) * 128);
        vB1 = *(const float4*)(vsrc1 + (size_t)(tile + 1) * 128);
    };
    auto write_pair = [&](int base) {              // writes bufs base, base+1
        *(float4*)(&Ks[base][wads0]) = kA0;  *(float4*)(&Ks[base][wads1]) = kA1;
        *(float4*)(&Vs[base][wads0]) = vA0;  *(float4*)(&Vs[base][wads1]) = vA1;
        *(float4*)(&Ks[base + 1][wads0]) = kB0;  *(float4*)(&Ks[base + 1][wads1]) = kB1;
        *(float4*)(&Vs[base + 1][wads0]) = vB0;  *(float4*)(&Vs[base + 1][wads1]) = vB1;
    };

    auto qk = [&](int buf, f32x16& s0h, f32x16& s1h) {
        s0h = f32x16{}; s1h = f32x16{};
        const char* base0 = Ks[buf] + lq * 128;
        const char* base1 = Ks[buf] + (32 + lq) * 128;
        const int sw0 = (lq & 7) << 4;
        __builtin_amdgcn_s_setprio(1);
        #pragma unroll
        for (int t = 0; t < 4; t++) {
            bf16x8 kf0 = *(const bf16x8*)(base0 + ((t * 32 + hi * 16) ^ sw0));
            s0h = __builtin_amdgcn_mfma_f32_32x32x16_bf16(kf0, qf[t], s0h, 0, 0, 0);
        }
        #pragma unroll
        for (int t = 0; t < 4; t++) {
            bf16x8 kf1 = *(const bf16x8*)(base1 + ((t * 32 + hi * 16) ^ sw0));
            s1h = __builtin_amdgcn_mfma_f32_32x32x16_bf16(kf1, qf[t], s1h, 0, 0, 0);
        }
        __builtin_amdgcn_s_setprio(0);
    };

    auto sm_exp = [&](f32x16& a, f32x16& b) {
        #pragma unroll
        for (int r = 0; r < 16; r += 4) {
            a[r + 0] = exp2_hw(a[r + 0]); a[r + 1] = exp2_hw(a[r + 1]);
            a[r + 2] = exp2_hw(a[r + 2]); a[r + 3] = exp2_hw(a[r + 3]);
            b[r + 0] = exp2_hw(b[r + 0]); b[r + 1] = exp2_hw(b[r + 1]);
            b[r + 2] = exp2_hw(b[r + 2]); b[r + 3] = exp2_hw(b[r + 3]);
            ls0 += a[r + 0] + b[r + 0];
            ls1 += a[r + 1] + b[r + 1];
            ls2 += a[r + 2] + b[r + 2];
            ls3 += a[r + 3] + b[r + 3];
        }
    };

    auto pv = [&](int buf, const f32x16& a, const f32x16& b) {
        unsigned pw0[8], pw1[8];
        #pragma unroll
        for (int M = 0; M < 4; M++) {
            const int u = M * 4;
            pw0[M] = cvtpk_bf16(a[u + 0], a[u + 1]);
            pw1[M] = cvtpk_bf16(a[u + 2], a[u + 3]);
            pw0[M + 4] = cvtpk_bf16(b[u + 0], b[u + 1]);
            pw1[M + 4] = cvtpk_bf16(b[u + 2], b[u + 3]);
        }
        __builtin_amdgcn_s_setprio(1);
        #pragma unroll
        for (int t = 0; t < 4; t++) {
            u32x2 s0p = __builtin_amdgcn_permlane32_swap(pw0[2 * t], pw0[2 * t + 1], false, false);
            u32x2 s1p = __builtin_amdgcn_permlane32_swap(pw1[2 * t], pw1[2 * t + 1], false, false);
            union { unsigned u[4]; bf16x8 v; } af;
            af.u[0] = s0p.x; af.u[1] = s1p.x; af.u[2] = s0p.y; af.u[3] = s1p.y;
            #pragma unroll
            for (int dh = 0; dh < 2; dh++) {
                const int row = dh * 32 + lq;
                bf16x8 vf = *(const bf16x8*)(&Vs[buf][row * 128 + ((t * 32 + hi * 16) ^ ((row & 7) << 4))]);
                yacc[dh] = __builtin_amdgcn_mfma_f32_32x32x16_bf16(af.v, vf, yacc[dh], 0, 0, 0);
            }
        }
        __builtin_amdgcn_s_setprio(0);
    };

    // prologue: tiles 0,1 -> bufs 0,1; tiles 2,3 held in regs
    f32x16 sA0, sA1, sB0, sB1;
    load_pair(0); write_pair(0);
    load_pair(2);
    __syncthreads();

    // pair loop: 16 pairs, ONE barrier each
    for (int p = 0; p < 16; ++p) {
        const int base = (p & 1) * 2;
        qk(base, sA0, sA1);          // tile 2p
        qk(base + 1, sB0, sB1);      // tile 2p+1 (independent -> 16-MFMA ILP window)
        if (p < 15) {
            asm volatile("s_waitcnt vmcnt(0)" ::: "memory");  // regs (tiles 2p+2,2p+3, loaded pair p-1) landed
            write_pair(base ^ 2);
            if (p < 14) load_pair(2 * p + 4);
        }
        sm_exp(sA0, sA1);
        pv(base, sA0, sA1);
        sm_exp(sB0, sB1);
        pv(base + 1, sB0, sB1);
        asm volatile("s_waitcnt lgkmcnt(0)" ::: "memory");
        __builtin_amdgcn_s_barrier();
        __builtin_amdgcn_sched_barrier(0);
    }

    float lsum = (ls0 + ls1) + (ls2 + ls3);
    lsum += __shfl_xor(lsum, 32);
    float inv = 1.0f / lsum;
    if (hi == 0) bc[w][lq] = inv;
    asm volatile("s_waitcnt lgkmcnt(0)" ::: "memory");
    __builtin_amdgcn_sched_barrier(0);

    const int b = head >> 4, h16 = head & 15;
    const size_t rowbase = (size_t)b * T_SEQ + q0;
    #pragma unroll
    for (int r = 0; r < 16; r++) {
        const int crow = (r & 3) + 8 * (r >> 2) + 4 * hi;
        const float iv = bc[w][crow];
        const size_t row = rowbase + crow;
        Y[row * C_DIM + h16 * DHD + lq]      = __float2bfloat16(yacc[0][r] * iv);
        Y[row * C_DIM + h16 * DHD + 32 + lq] = __float2bfloat16(yacc[1][r] * iv);
    }
}

// ---------------- launch ----------------
extern "C" void kernel_launch(void* const* d_in, const int* in_sizes, int n_in,
                              void* d_out, int out_size, void* d_ws, size_t ws_size,
                              hipStream_t stream) {
    (void)in_sizes; (void)n_in; (void)out_size; (void)ws_size;
    const float* x  = (const float*)d_in[0];
    const float* Wq = (const float*)d_in[1];
    const float* bq = (const float*)d_in[2];
    const float* Wk = (const float*)d_in[3];
    const float* bk = (const float*)d_in[4];
    const float* Wv = (const float*)d_in[5];
    const float* bv = (const float*)d_in[6];
    const float* Wp = (const float*)d_in[7];
    const float* bp = (const float*)d_in[8];
    float* out = (float*)d_out;

    char* ws = (char*)d_ws;
    const size_t MC = (size_t)4096 * C_DIM;
    const size_t CC = (size_t)C_DIM * C_DIM;
    __hip_bfloat16* xb  = (__hip_bfloat16*)ws;  ws += MC * 2;
    __hip_bfloat16* wf  = (__hip_bfloat16*)ws;  ws += 3 * CC * 2;   // Wq|Wk|Wv fused
    __hip_bfloat16* wpb = (__hip_bfloat16*)ws;  ws += CC * 2;
    __hip_bfloat16* qb  = (__hip_bfloat16*)ws;  ws += MC * 2;
    __hip_bfloat16* kb  = (__hip_bfloat16*)ws;  ws += MC * 2;
    __hip_bfloat16* vtb = (__hip_bfloat16*)ws;  ws += MC * 2;
    __hip_bfloat16* yb  = (__hip_bfloat16*)ws;  ws += MC * 2;

    cvt_all<<<8192, 256, 0, stream>>>(x, Wq, Wk, Wv, Wp, xb, wf, wpb);

    gemm_qkv<<<256, 512, 0, stream>>>(xb, wf, bq, bk, bv, qb, kb, vtb);

    attn11<<<512, 256, 0, stream>>>(qb, kb, vtb, yb);

    gemm_proj2<<<256, 512, 0, stream>>>(yb, wpb, bp, out);
}

// Round 17
// 113.047 us; speedup vs baseline: 1.0667x; 1.0667x over previous
//
#include <hip/hip_runtime.h>
#include <hip/hip_bf16.h>

typedef __attribute__((ext_vector_type(4))) float f32x4;
typedef __attribute__((ext_vector_type(16))) float f32x16;
typedef __attribute__((ext_vector_type(8))) short bf16x8;
typedef __attribute__((ext_vector_type(2))) unsigned int u32x2;

#define T_SEQ 2048
#define C_DIM 1024
#define NH 16
#define DHD 64

__device__ __forceinline__ unsigned cvtpk_bf16(float lo, float hi) {
    unsigned r;
    asm("v_cvt_pk_bf16_f32 %0, %1, %2" : "=v"(r) : "v"(lo), "v"(hi));
    return r;
}

// hardware 2^x
__device__ __forceinline__ float exp2_hw(float x) {
    float r;
    asm("v_exp_f32 %0, %1" : "=v"(r) : "v"(x));
    return r;
}

// async global->LDS, 16B per lane. LDS dest = wave-uniform base; HW adds lane*16.
__device__ __forceinline__ void async_copy16(void* lds, const void* g) {
    __builtin_amdgcn_global_load_lds(
        (const __attribute__((address_space(1))) unsigned int*)(uintptr_t)g,
        (__attribute__((address_space(3))) unsigned int*)(unsigned int)(uintptr_t)lds,
        16, 0, 0);
}

// ---------------- fused fp32 -> bf16 convert (packed 8B stores) ----------------
__global__ __launch_bounds__(256) void cvt_all(const float* __restrict__ x,
                                               const float* __restrict__ Wq, const float* __restrict__ Wk,
                                               const float* __restrict__ Wv, const float* __restrict__ Wp,
                                               __hip_bfloat16* __restrict__ xb,
                                               __hip_bfloat16* __restrict__ wf,
                                               __hip_bfloat16* __restrict__ wpb) {
    int i = blockIdx.x * blockDim.x + threadIdx.x;   // float4 index
    const float* src; __hip_bfloat16* dst; int off;
    if (i < 1048576) { src = x; dst = xb; off = i; }
    else {
        int j = i - 1048576; int wi = j >> 18; off = j & 262143;
        switch (wi) {
            case 0:  src = Wq; dst = wf;           break;
            case 1:  src = Wk; dst = wf + 1048576; break;
            case 2:  src = Wv; dst = wf + 2097152; break;
            default: src = Wp; dst = wpb;          break;
        }
    }
    float4 v = *(const float4*)(src + (size_t)off * 4);
    union { __hip_bfloat16 h[4]; u32x2 u; } p;
    p.h[0] = __float2bfloat16(v.x); p.h[1] = __float2bfloat16(v.y);
    p.h[2] = __float2bfloat16(v.z); p.h[3] = __float2bfloat16(v.w);
    *(u32x2*)(dst + (size_t)off * 4) = p.u;
}

// ---------------- QKV GEMM: 128x384 tile, BK=64, 6-phase counted-vmcnt schedule, 256 blocks ----------------
__global__ __launch_bounds__(512) void gemm_qkv(const __hip_bfloat16* __restrict__ A,
                                                const __hip_bfloat16* __restrict__ Bw,
                                                const float* __restrict__ biasq,
                                                const float* __restrict__ biask,
                                                const float* __restrict__ biasv,
                                                __hip_bfloat16* __restrict__ oq,
                                                __hip_bfloat16* __restrict__ okk,
                                                __hip_bfloat16* __restrict__ ovt) {
    __shared__ __align__(16) char lds[131072]; // A: 2buf x 2half x 8KB @0; B: 2buf x 2half x 24KB @32768

    const int wg = ((int)blockIdx.x & 7) * 32 + ((int)blockIdx.x >> 3);
    const int m0 = (wg & 31) * 128;   // 32 m-tiles
    const int n0 = (wg >> 5) * 384;   // 8 n-tiles

    const int tid = threadIdx.x;
    const int w = tid >> 6, l = tid & 63;
    const int wr = w >> 2, wc = w & 3;      // wave grid 2M x 4N: 64 rows x 96 cols per wave
    const int lg = l >> 4, lr = l & 15;

    const int sr0 = tid >> 3;
    const int sc0 = (tid & 7) * 16;
    const int gc0 = sc0 ^ ((sr0 & 7) << 4);
    const size_t goff = (size_t)sr0 * 2048 + gc0;

    const char* Ag = (const char*)A + (size_t)m0 * 2048;
    const char* Bg = (const char*)Bw + (size_t)n0 * 2048;

    auto STAGE_A = [&](int buf, int half, int kt) {
        const char* g = Ag + (size_t)(half * 64) * 2048 + kt * 128 + goff;
        char* d = lds + (buf * 2 + half) * 8192 + w * 1024;
        async_copy16(d, g);
    };
    auto STAGE_B = [&](int buf, int half, int kt) {
        #pragma unroll
        for (int p = 0; p < 3; p++) {
            const char* g = Bg + (size_t)(half * 192 + p * 64) * 2048 + kt * 128 + goff;
            char* d = lds + 32768 + (buf * 2 + half) * 24576 + p * 8192 + w * 1024;
            async_copy16(d, g);
        }
    };

    const int sw = (lr & 7) << 4;
    auto LDA = [&](bf16x8* af, int buf) {
        const char* base = lds + (buf * 2 + wr) * 8192;
        #pragma unroll
        for (int m = 0; m < 4; m++) {
            const int r = m * 16 + lr;
            #pragma unroll
            for (int kk = 0; kk < 2; kk++)
                af[m * 2 + kk] = *(const bf16x8*)(base + r * 128 + ((kk * 64 + lg * 16) ^ sw));
        }
    };
    auto LDB = [&](bf16x8* bfv, int buf, int nq) {
        const char* base = lds + 32768 + (buf * 2 + (wc >> 1)) * 24576;
        #pragma unroll
        for (int n = 0; n < 2; n++) {
            const int r = (wc & 1) * 96 + (nq * 2 + n) * 16 + lr;
            #pragma unroll
            for (int kk = 0; kk < 2; kk++)
                bfv[n * 2 + kk] = *(const bf16x8*)(base + r * 128 + ((kk * 64 + lg * 16) ^ sw));
        }
    };

    f32x4 acc[4][6] = {};
    auto MF = [&](const bf16x8* af, const bf16x8* bfv, int nq) {
        #pragma unroll
        for (int m = 0; m < 4; m++)
            #pragma unroll
            for (int n = 0; n < 2; n++)
                #pragma unroll
                for (int kk = 0; kk < 2; kk++)
                    acc[m][nq * 2 + n] = __builtin_amdgcn_mfma_f32_16x16x32_bf16(
                        af[m * 2 + kk], bfv[n * 2 + kk], acc[m][nq * 2 + n], 0, 0, 0);
    };

#define PH_OPEN()  __builtin_amdgcn_sched_barrier(0); \
                   __builtin_amdgcn_s_barrier(); \
                   asm volatile("s_waitcnt lgkmcnt(0)" ::: "memory"); \
                   __builtin_amdgcn_sched_barrier(0); \
                   __builtin_amdgcn_s_setprio(1);
#define PH_CLOSE() __builtin_amdgcn_s_setprio(0); \
                   __builtin_amdgcn_sched_barrier(0); \
                   __builtin_amdgcn_s_barrier();
#define PH_CLOSE_VM2() __builtin_amdgcn_s_setprio(0); \
                   asm volatile("s_waitcnt vmcnt(2)" ::: "memory"); \
                   __builtin_amdgcn_sched_barrier(0); \
                   __builtin_amdgcn_s_barrier();
#define PH_CLOSE_VM5() __builtin_amdgcn_s_setprio(0); \
                   asm volatile("s_waitcnt vmcnt(5)" ::: "memory"); \
                   __builtin_amdgcn_sched_barrier(0); \
                   __builtin_amdgcn_s_barrier();

    bf16x8 af[8], bfA[4], bfB[4], bfC[4];

    STAGE_B(0, 0, 0); STAGE_B(0, 1, 0); STAGE_A(0, 0, 0); STAGE_A(0, 1, 0);
    STAGE_A(1, 0, 1); STAGE_A(1, 1, 1); STAGE_B(1, 0, 1);
    asm volatile("s_waitcnt vmcnt(5)" ::: "memory");
    __builtin_amdgcn_sched_barrier(0);
    __builtin_amdgcn_s_barrier();

    for (int it = 0; it < 8; ++it) {
        const int t1 = 2 * it + 1;
        const int c2 = (2 * it + 2 < 16) ? 2 * it + 2 : 14;
        const int c3 = (2 * it + 3 < 16) ? 2 * it + 3 : 15;
        const int b2 = c2 & 1, b3 = c3 & 1;

        LDA(af, 0); LDB(bfA, 0, 0);
        STAGE_B(1, 1, t1);
        PH_OPEN(); MF(af, bfA, 0); PH_CLOSE();
        LDB(bfB, 0, 1);
        STAGE_A(b2, 0, c2); STAGE_A(b2, 1, c2);
        PH_OPEN(); MF(af, bfB, 1); PH_CLOSE();
        LDB(bfC, 0, 2);
        PH_OPEN(); MF(af, bfC, 2); PH_CLOSE_VM2();

        LDA(af, 1); LDB(bfA, 1, 0);
        STAGE_B(b2, 0, c2);
        PH_OPEN(); MF(af, bfA, 0); PH_CLOSE();
        LDB(bfB, 1, 1);
        STAGE_B(b2, 1, c2); STAGE_A(b3, 0, c3); STAGE_A(b3, 1, c3);
        PH_OPEN(); MF(af, bfB, 1); PH_CLOSE();
        LDB(bfC, 1, 2);
        STAGE_B(b3, 0, c3);
        PH_OPEN(); MF(af, bfC, 2); PH_CLOSE_VM5();
    }
#undef PH_OPEN
#undef PH_CLOSE
#undef PH_CLOSE_VM2
#undef PH_CLOSE_VM5

    #pragma unroll
    for (int m = 0; m < 4; m++) {
        const int rowb = m0 + wr * 64 + m * 16 + lg * 4;
        const int b = rowb >> 11, t0r = rowb & 2047;
        #pragma unroll
        for (int nf = 0; nf < 6; nf++) {
            const int col = n0 + wc * 96 + nf * 16 + lr;
            const int proj = col >> 10;
            const int colL = col & 1023;
            const int hh = colL >> 6, dd = colL & 63;
            if (proj < 2) {
                const float* bias = (proj == 0) ? biasq : biask;
                const float bsc = (proj == 0) ? 0.125f * 1.4426950408889634f : 1.0f;
                __hip_bfloat16* dst = (proj == 0) ? oq : okk;
                #pragma unroll
                for (int rr = 0; rr < 4; rr++) {
                    const int row = rowb + rr;
                    float val = (acc[m][nf][rr] + bias[colL]) * bsc;
                    dst[(((size_t)(b * NH + hh)) * T_SEQ + (row & 2047)) * DHD + dd] = __float2bfloat16(val);
                }
            } else {
                const float bv = biasv[colL];
                union { __hip_bfloat16 h[4]; u32x2 u; } p;
                #pragma unroll
                for (int rr = 0; rr < 4; rr++)
                    p.h[rr] = __float2bfloat16(acc[m][nf][rr] + bv);
                *(u32x2*)&ovt[(((size_t)(b * NH + hh)) * DHD + dd) * T_SEQ + t0r] = p.u;
            }
        }
    }
}

// ---------------- proj GEMM v2: 128x128 tile, BK=64, 4-phase counted-vmcnt, 256 blocks ----------------
__global__ __launch_bounds__(512) void gemm_proj2(const __hip_bfloat16* __restrict__ A,
                                                  const __hip_bfloat16* __restrict__ Bw,
                                                  const float* __restrict__ biasp,
                                                  float* __restrict__ outf) {
    __shared__ __align__(16) char lds[65536]; // A: 2buf x 2half x 8KB @0; B same @32768

    const int wg = ((int)blockIdx.x & 7) * 32 + ((int)blockIdx.x >> 3); // bijective, 256%8==0
    const int m0 = (wg & 31) * 128;
    const int n0 = (wg >> 5) * 128;

    const int tid = threadIdx.x;
    const int w = tid >> 6, l = tid & 63;
    const int wr = w >> 2, wc = w & 3;
    const int lg = l >> 4, lr = l & 15;

    const int sr0 = tid >> 3;
    const int sc0 = (tid & 7) * 16;
    const int gc0 = sc0 ^ ((sr0 & 7) << 4);
    const size_t goff = (size_t)sr0 * 2048 + gc0;

    const char* Ag = (const char*)A + (size_t)m0 * 2048;
    const char* Bg = (const char*)Bw + (size_t)n0 * 2048;

    auto STAGE_A = [&](int buf, int half, int kt) {
        const char* g = Ag + (size_t)(half * 64) * 2048 + kt * 128 + goff;
        char* d = lds + (buf * 2 + half) * 8192 + w * 1024;
        async_copy16(d, g);
    };
    auto STAGE_B = [&](int buf, int half, int kt) {
        const char* g = Bg + (size_t)(half * 64) * 2048 + kt * 128 + goff;
        char* d = lds + 32768 + (buf * 2 + half) * 8192 + w * 1024;
        async_copy16(d, g);
    };

    const int sw = (lr & 7) << 4;
    auto LDA = [&](bf16x8* af, int buf) {
        const char* base = lds + (buf * 2 + wr) * 8192;
        #pragma unroll
        for (int m = 0; m < 4; m++) {
            const int r = m * 16 + lr;
            #pragma unroll
            for (int kk = 0; kk < 2; kk++)
                af[m * 2 + kk] = *(const bf16x8*)(base + r * 128 + ((kk * 64 + lg * 16) ^ sw));
        }
    };
    auto LDB = [&](bf16x8* bfv, int buf, int n) {
        const char* base = lds + 32768 + (buf * 2 + (wc >> 1)) * 8192;
        const int r = (wc & 1) * 32 + n * 16 + lr;
        #pragma unroll
        for (int kk = 0; kk < 2; kk++)
            bfv[kk] = *(const bf16x8*)(base + r * 128 + ((kk * 64 + lg * 16) ^ sw));
    };

    f32x4 acc[4][2] = {};
    auto MF = [&](const bf16x8* af, const bf16x8* bfv, int n) {
        #pragma unroll
        for (int m = 0; m < 4; m++)
            #pragma unroll
            for (int kk = 0; kk < 2; kk++)
                acc[m][n] = __builtin_amdgcn_mfma_f32_16x16x32_bf16(
                    af[m * 2 + kk], bfv[kk], acc[m][n], 0, 0, 0);
    };

#define PH_OPEN()  __builtin_amdgcn_sched_barrier(0); \
                   __builtin_amdgcn_s_barrier(); \
                   asm volatile("s_waitcnt lgkmcnt(0)" ::: "memory"); \
                   __builtin_amdgcn_sched_barrier(0); \
                   __builtin_amdgcn_s_setprio(1);
#define PH_CLOSE() __builtin_amdgcn_s_setprio(0); \
                   __builtin_amdgcn_sched_barrier(0); \
                   __builtin_amdgcn_s_barrier();
#define PH_CLOSE_VM2() __builtin_amdgcn_s_setprio(0); \
                   asm volatile("s_waitcnt vmcnt(2)" ::: "memory"); \
                   __builtin_amdgcn_sched_barrier(0); \
                   __builtin_amdgcn_s_barrier();

    bf16x8 af[8], bf0[2], bf1[2];

    STAGE_B(0, 0, 0); STAGE_B(0, 1, 0); STAGE_A(0, 0, 0); STAGE_A(0, 1, 0);
    STAGE_A(1, 0, 1); STAGE_A(1, 1, 1);
    asm volatile("s_waitcnt vmcnt(2)" ::: "memory");
    __builtin_amdgcn_sched_barrier(0);
    __builtin_amdgcn_s_barrier();

    for (int it = 0; it < 8; ++it) {
        const int t1 = 2 * it + 1;
        const int c2 = (2 * it + 2 < 16) ? 2 * it + 2 : 14;
        const int c3 = (2 * it + 3 < 16) ? 2 * it + 3 : 15;
        const int b2 = c2 & 1, b3 = c3 & 1;

        LDA(af, 0); LDB(bf0, 0, 0);
        STAGE_B(1, 0, t1); STAGE_B(1, 1, t1);
        PH_OPEN(); MF(af, bf0, 0); PH_CLOSE();
        LDB(bf1, 0, 1);
        STAGE_A(b2, 0, c2); STAGE_A(b2, 1, c2);
        PH_OPEN(); MF(af, bf1, 1); PH_CLOSE_VM2();

        LDA(af, 1); LDB(bf0, 1, 0);
        STAGE_B(b2, 0, c2); STAGE_B(b2, 1, c2);
        PH_OPEN(); MF(af, bf0, 0); PH_CLOSE();
        LDB(bf1, 1, 1);
        STAGE_A(b3, 0, c3); STAGE_A(b3, 1, c3);
        PH_OPEN(); MF(af, bf1, 1); PH_CLOSE_VM2();
    }
#undef PH_OPEN
#undef PH_CLOSE
#undef PH_CLOSE_VM2

    #pragma unroll
    for (int m = 0; m < 4; m++)
        #pragma unroll
        for (int n = 0; n < 2; n++)
            #pragma unroll
            for (int r = 0; r < 4; r++) {
                int row = m0 + wr * 64 + m * 16 + lg * 4 + r;
                int col = n0 + wc * 32 + n * 16 + lr;
                outf[(size_t)row * C_DIM + col] = acc[m][n][r] + biasp[col];
            }
}

// ---------------- flash attention (attn8, proven) ----------------
__global__ __launch_bounds__(256) void attn8(const __hip_bfloat16* __restrict__ Q,
                                             const __hip_bfloat16* __restrict__ K,
                                             const __hip_bfloat16* __restrict__ Vt,
                                             __hip_bfloat16* __restrict__ Y) {
    const int bid = blockIdx.x;
    const int xcd = bid & 7, slot = bid >> 3;
    const int head = xcd * 4 + (slot & 3);
    const int qblk = slot >> 2;

    const int tid = threadIdx.x;
    const int w = tid >> 6, l = tid & 63;
    const int lq = l & 31, hi = l >> 5;
    const int q0 = qblk * 128 + w * 32;

    __shared__ __align__(16) char Ks[3][8192];
    __shared__ __align__(16) char Vs[3][8192];
    __shared__ float bc[4][32];

    const char* Kb = (const char*)(K + (size_t)head * T_SEQ * DHD);
    const char* Vb = (const char*)(Vt + (size_t)head * DHD * T_SEQ);

    bf16x8 qf[4];
    {
        const char* qrow = (const char*)(Q + ((size_t)head * T_SEQ + q0 + lq) * DHD);
        #pragma unroll
        for (int t = 0; t < 4; t++) qf[t] = *(const bf16x8*)(qrow + t * 32 + hi * 16);
    }

    f32x16 yacc[2] = {};
    float ls0 = 0.f, ls1 = 0.f, ls2 = 0.f, ls3 = 0.f;

    const int o0 = (2 * w) * 1024 + l * 16;
    const int o1 = o0 + 1024;
    const int r0 = o0 >> 7, c0b = o0 & 127;
    const int r1 = o1 >> 7, c1b = o1 & 127;
    const int wads0 = r0 * 128 + (c0b ^ ((r0 & 7) << 4));
    const int wads1 = r1 * 128 + (c1b ^ ((r1 & 7) << 4));
    const char* vsrc0 = Vb + (size_t)r0 * (T_SEQ * 2) + c0b;
    const char* vsrc1 = Vb + (size_t)r1 * (T_SEQ * 2) + c1b;

    float4 kreg0, kreg1, vreg0, vreg1;
    auto stage_load = [&](int tile) {
        const char* kb2 = Kb + (size_t)tile * 8192;
        kreg0 = *(const float4*)(kb2 + o0);
        kreg1 = *(const float4*)(kb2 + o1);
        vreg0 = *(const float4*)(vsrc0 + (size_t)tile * 128);
        vreg1 = *(const float4*)(vsrc1 + (size_t)tile * 128);
    };
    auto stage_write = [&](int buf) {
        *(float4*)(&Ks[buf][wads0]) = kreg0;
        *(float4*)(&Ks[buf][wads1]) = kreg1;
        *(float4*)(&Vs[buf][wads0]) = vreg0;
        *(float4*)(&Vs[buf][wads1]) = vreg1;
    };

    auto qk = [&](int buf, f32x16& s0h, f32x16& s1h) {
        s0h = f32x16{}; s1h = f32x16{};
        const char* base0 = Ks[buf] + lq * 128;
        const char* base1 = Ks[buf] + (32 + lq) * 128;
        const int sw0 = (lq & 7) << 4;
        __builtin_amdgcn_s_setprio(1);
        #pragma unroll
        for (int t = 0; t < 4; t++) {
            bf16x8 kf0 = *(const bf16x8*)(base0 + ((t * 32 + hi * 16) ^ sw0));
            s0h = __builtin_amdgcn_mfma_f32_32x32x16_bf16(kf0, qf[t], s0h, 0, 0, 0);
        }
        #pragma unroll
        for (int t = 0; t < 4; t++) {
            bf16x8 kf1 = *(const bf16x8*)(base1 + ((t * 32 + hi * 16) ^ sw0));
            s1h = __builtin_amdgcn_mfma_f32_32x32x16_bf16(kf1, qf[t], s1h, 0, 0, 0);
        }
        __builtin_amdgcn_s_setprio(0);
    };

    auto sm_exp = [&](f32x16& a, f32x16& b) {
        #pragma unroll
        for (int r = 0; r < 16; r += 4) {
            a[r + 0] = exp2_hw(a[r + 0]); a[r + 1] = exp2_hw(a[r + 1]);
            a[r + 2] = exp2_hw(a[r + 2]); a[r + 3] = exp2_hw(a[r + 3]);
            b[r + 0] = exp2_hw(b[r + 0]); b[r + 1] = exp2_hw(b[r + 1]);
            b[r + 2] = exp2_hw(b[r + 2]); b[r + 3] = exp2_hw(b[r + 3]);
            ls0 += a[r + 0] + b[r + 0];
            ls1 += a[r + 1] + b[r + 1];
            ls2 += a[r + 2] + b[r + 2];
            ls3 += a[r + 3] + b[r + 3];
        }
    };

    auto pv = [&](int buf, const f32x16& a, const f32x16& b) {
        unsigned pw0[8], pw1[8];
        #pragma unroll
        for (int M = 0; M < 4; M++) {
            const int u = M * 4;
            pw0[M] = cvtpk_bf16(a[u + 0], a[u + 1]);
            pw1[M] = cvtpk_bf16(a[u + 2], a[u + 3]);
            pw0[M + 4] = cvtpk_bf16(b[u + 0], b[u + 1]);
            pw1[M + 4] = cvtpk_bf16(b[u + 2], b[u + 3]);
        }
        __builtin_amdgcn_s_setprio(1);
        #pragma unroll
        for (int t = 0; t < 4; t++) {
            u32x2 s0p = __builtin_amdgcn_permlane32_swap(pw0[2 * t], pw0[2 * t + 1], false, false);
            u32x2 s1p = __builtin_amdgcn_permlane32_swap(pw1[2 * t], pw1[2 * t + 1], false, false);
            union { unsigned u[4]; bf16x8 v; } af;
            af.u[0] = s0p.x; af.u[1] = s1p.x; af.u[2] = s0p.y; af.u[3] = s1p.y;
            #pragma unroll
            for (int dh = 0; dh < 2; dh++) {
                const int row = dh * 32 + lq;
                bf16x8 vf = *(const bf16x8*)(&Vs[buf][row * 128 + ((t * 32 + hi * 16) ^ ((row & 7) << 4))]);
                yacc[dh] = __builtin_amdgcn_mfma_f32_32x32x16_bf16(af.v, vf, yacc[dh], 0, 0, 0);
            }
        }
        __builtin_amdgcn_s_setprio(0);
    };

    f32x16 sA0, sA1, sB0, sB1;
    stage_load(0); stage_write(0);
    stage_load(1); stage_write(1);
    stage_load(2);
    __syncthreads();
    qk(0, sA0, sA1);

    for (int t = 0; t < 32; t += 2) {
        qk((t + 1) % 3, sB0, sB1);
        if (t + 2 < 32) {
            asm volatile("s_waitcnt vmcnt(0)" ::: "memory");
            stage_write((t + 2) % 3);
            if (t + 3 < 32) stage_load(t + 3);
        }
        sm_exp(sA0, sA1);
        pv(t % 3, sA0, sA1);
        asm volatile("s_waitcnt lgkmcnt(0)" ::: "memory");
        __builtin_amdgcn_s_barrier();
        __builtin_amdgcn_sched_barrier(0);

        const int t1 = t + 1;
        if (t1 + 1 < 32) qk((t1 + 1) % 3, sA0, sA1);
        if (t1 + 2 < 32) {
            asm volatile("s_waitcnt vmcnt(0)" ::: "memory");
            stage_write((t1 + 2) % 3);
            if (t1 + 3 < 32) stage_load(t1 + 3);
        }
        sm_exp(sB0, sB1);
        pv(t1 % 3, sB0, sB1);
        asm volatile("s_waitcnt lgkmcnt(0)" ::: "memory");
        __builtin_amdgcn_s_barrier();
        __builtin_amdgcn_sched_barrier(0);
    }

    float lsum = (ls0 + ls1) + (ls2 + ls3);
    lsum += __shfl_xor(lsum, 32);
    float inv = 1.0f / lsum;
    if (hi == 0) bc[w][lq] = inv;
    asm volatile("s_waitcnt lgkmcnt(0)" ::: "memory");
    __builtin_amdgcn_sched_barrier(0);

    const int b = head >> 4, h16 = head & 15;
    const size_t rowbase = (size_t)b * T_SEQ + q0;
    #pragma unroll
    for (int r = 0; r < 16; r++) {
        const int crow = (r & 3) + 8 * (r >> 2) + 4 * hi;
        const float iv = bc[w][crow];
        const size_t row = rowbase + crow;
        Y[row * C_DIM + h16 * DHD + lq]      = __float2bfloat16(yacc[0][r] * iv);
        Y[row * C_DIM + h16 * DHD + 32 + lq] = __float2bfloat16(yacc[1][r] * iv);
    }
}

// ---------------- launch ----------------
extern "C" void kernel_launch(void* const* d_in, const int* in_sizes, int n_in,
                              void* d_out, int out_size, void* d_ws, size_t ws_size,
                              hipStream_t stream) {
    (void)in_sizes; (void)n_in; (void)out_size; (void)ws_size;
    const float* x  = (const float*)d_in[0];
    const float* Wq = (const float*)d_in[1];
    const float* bq = (const float*)d_in[2];
    const float* Wk = (const float*)d_in[3];
    const float* bk = (const float*)d_in[4];
    const float* Wv = (const float*)d_in[5];
    const float* bv = (const float*)d_in[6];
    const float* Wp = (const float*)d_in[7];
    const float* bp = (const float*)d_in[8];
    float* out = (float*)d_out;

    char* ws = (char*)d_ws;
    const size_t MC = (size_t)4096 * C_DIM;
    const size_t CC = (size_t)C_DIM * C_DIM;
    __hip_bfloat16* xb  = (__hip_bfloat16*)ws;  ws += MC * 2;
    __hip_bfloat16* wf  = (__hip_bfloat16*)ws;  ws += 3 * CC * 2;   // Wq|Wk|Wv fused
    __hip_bfloat16* wpb = (__hip_bfloat16*)ws;  ws += CC * 2;
    __hip_bfloat16* qb  = (__hip_bfloat16*)ws;  ws += MC * 2;
    __hip_bfloat16* kb  = (__hip_bfloat16*)ws;  ws += MC * 2;
    __hip_bfloat16* vtb = (__hip_bfloat16*)ws;  ws += MC * 2;
    __hip_bfloat16* yb  = (__hip_bfloat16*)ws;  ws += MC * 2;

    cvt_all<<<8192, 256, 0, stream>>>(x, Wq, Wk, Wv, Wp, xb, wf, wpb);

    gemm_qkv<<<256, 512, 0, stream>>>(xb, wf, bq, bk, bv, qb, kb, vtb);

    attn8<<<512, 256, 0, stream>>>(qb, kb, vtb, yb);

    gemm_proj2<<<256, 512, 0, stream>>>(yb, wpb, bp, out);
}

// Round 18
// 112.625 us; speedup vs baseline: 1.0707x; 1.0038x over previous
//
#include <hip/hip_runtime.h>
#include <hip/hip_bf16.h>

typedef __attribute__((ext_vector_type(4))) float f32x4;
typedef __attribute__((ext_vector_type(16))) float f32x16;
typedef __attribute__((ext_vector_type(8))) short bf16x8;
typedef __attribute__((ext_vector_type(2))) unsigned int u32x2;

#define T_SEQ 2048
#define C_DIM 1024
#define NH 16
#define DHD 64
#define ROWB 136   // attn LDS row stride: 2-bank advance/row -> 2-way (free) aliasing

__device__ __forceinline__ unsigned cvtpk_bf16(float lo, float hi) {
    unsigned r;
    asm("v_cvt_pk_bf16_f32 %0, %1, %2" : "=v"(r) : "v"(lo), "v"(hi));
    return r;
}

// hardware 2^x
__device__ __forceinline__ float exp2_hw(float x) {
    float r;
    asm("v_exp_f32 %0, %1" : "=v"(r) : "v"(x));
    return r;
}

// async global->LDS, 16B per lane. LDS dest = wave-uniform base; HW adds lane*16.
__device__ __forceinline__ void async_copy16(void* lds, const void* g) {
    __builtin_amdgcn_global_load_lds(
        (const __attribute__((address_space(1))) unsigned int*)(uintptr_t)g,
        (__attribute__((address_space(3))) unsigned int*)(unsigned int)(uintptr_t)lds,
        16, 0, 0);
}

// 16B fragment via two 8B LDS reads (8B-aligned; avoids b128 4-way bank conflicts)
__device__ __forceinline__ bf16x8 ld_frag8(const char* p) {
    union { float2 f[2]; bf16x8 v; } u;
    u.f[0] = *(const float2*)(p);
    u.f[1] = *(const float2*)(p + 8);
    return u.v;
}

// ---------------- fused fp32 -> bf16 convert (packed 8B stores) ----------------
__global__ __launch_bounds__(256) void cvt_all(const float* __restrict__ x,
                                               const float* __restrict__ Wq, const float* __restrict__ Wk,
                                               const float* __restrict__ Wv, const float* __restrict__ Wp,
                                               __hip_bfloat16* __restrict__ xb,
                                               __hip_bfloat16* __restrict__ wf,
                                               __hip_bfloat16* __restrict__ wpb) {
    int i = blockIdx.x * blockDim.x + threadIdx.x;   // float4 index
    const float* src; __hip_bfloat16* dst; int off;
    if (i < 1048576) { src = x; dst = xb; off = i; }
    else {
        int j = i - 1048576; int wi = j >> 18; off = j & 262143;
        switch (wi) {
            case 0:  src = Wq; dst = wf;           break;
            case 1:  src = Wk; dst = wf + 1048576; break;
            case 2:  src = Wv; dst = wf + 2097152; break;
            default: src = Wp; dst = wpb;          break;
        }
    }
    float4 v = *(const float4*)(src + (size_t)off * 4);
    union { __hip_bfloat16 h[4]; u32x2 u; } p;
    p.h[0] = __float2bfloat16(v.x); p.h[1] = __float2bfloat16(v.y);
    p.h[2] = __float2bfloat16(v.z); p.h[3] = __float2bfloat16(v.w);
    *(u32x2*)(dst + (size_t)off * 4) = p.u;
}

// ---------------- QKV GEMM: 128x384 tile, BK=64, 6-phase counted-vmcnt schedule, 256 blocks ----------------
__global__ __launch_bounds__(512) void gemm_qkv(const __hip_bfloat16* __restrict__ A,
                                                const __hip_bfloat16* __restrict__ Bw,
                                                const float* __restrict__ biasq,
                                                const float* __restrict__ biask,
                                                const float* __restrict__ biasv,
                                                __hip_bfloat16* __restrict__ oq,
                                                __hip_bfloat16* __restrict__ okk,
                                                __hip_bfloat16* __restrict__ ovt) {
    __shared__ __align__(16) char lds[131072]; // A: 2buf x 2half x 8KB @0; B: 2buf x 2half x 24KB @32768

    const int wg = ((int)blockIdx.x & 7) * 32 + ((int)blockIdx.x >> 3);
    const int m0 = (wg & 31) * 128;   // 32 m-tiles
    const int n0 = (wg >> 5) * 384;   // 8 n-tiles

    const int tid = threadIdx.x;
    const int w = tid >> 6, l = tid & 63;
    const int wr = w >> 2, wc = w & 3;      // wave grid 2M x 4N: 64 rows x 96 cols per wave
    const int lg = l >> 4, lr = l & 15;

    const int sr0 = tid >> 3;
    const int sc0 = (tid & 7) * 16;
    const int gc0 = sc0 ^ ((sr0 & 7) << 4);
    const size_t goff = (size_t)sr0 * 2048 + gc0;

    const char* Ag = (const char*)A + (size_t)m0 * 2048;
    const char* Bg = (const char*)Bw + (size_t)n0 * 2048;

    auto STAGE_A = [&](int buf, int half, int kt) {
        const char* g = Ag + (size_t)(half * 64) * 2048 + kt * 128 + goff;
        char* d = lds + (buf * 2 + half) * 8192 + w * 1024;
        async_copy16(d, g);
    };
    auto STAGE_B = [&](int buf, int half, int kt) {
        #pragma unroll
        for (int p = 0; p < 3; p++) {
            const char* g = Bg + (size_t)(half * 192 + p * 64) * 2048 + kt * 128 + goff;
            char* d = lds + 32768 + (buf * 2 + half) * 24576 + p * 8192 + w * 1024;
            async_copy16(d, g);
        }
    };

    const int sw = (lr & 7) << 4;
    auto LDA = [&](bf16x8* af, int buf) {
        const char* base = lds + (buf * 2 + wr) * 8192;
        #pragma unroll
        for (int m = 0; m < 4; m++) {
            const int r = m * 16 + lr;
            #pragma unroll
            for (int kk = 0; kk < 2; kk++)
                af[m * 2 + kk] = *(const bf16x8*)(base + r * 128 + ((kk * 64 + lg * 16) ^ sw));
        }
    };
    auto LDB = [&](bf16x8* bfv, int buf, int nq) {
        const char* base = lds + 32768 + (buf * 2 + (wc >> 1)) * 24576;
        #pragma unroll
        for (int n = 0; n < 2; n++) {
            const int r = (wc & 1) * 96 + (nq * 2 + n) * 16 + lr;
            #pragma unroll
            for (int kk = 0; kk < 2; kk++)
                bfv[n * 2 + kk] = *(const bf16x8*)(base + r * 128 + ((kk * 64 + lg * 16) ^ sw));
        }
    };

    f32x4 acc[4][6] = {};
    auto MF = [&](const bf16x8* af, const bf16x8* bfv, int nq) {
        #pragma unroll
        for (int m = 0; m < 4; m++)
            #pragma unroll
            for (int n = 0; n < 2; n++)
                #pragma unroll
                for (int kk = 0; kk < 2; kk++)
                    acc[m][nq * 2 + n] = __builtin_amdgcn_mfma_f32_16x16x32_bf16(
                        af[m * 2 + kk], bfv[n * 2 + kk], acc[m][nq * 2 + n], 0, 0, 0);
    };

#define PH_OPEN()  __builtin_amdgcn_sched_barrier(0); \
                   __builtin_amdgcn_s_barrier(); \
                   asm volatile("s_waitcnt lgkmcnt(0)" ::: "memory"); \
                   __builtin_amdgcn_sched_barrier(0); \
                   __builtin_amdgcn_s_setprio(1);
#define PH_CLOSE() __builtin_amdgcn_s_setprio(0); \
                   __builtin_amdgcn_sched_barrier(0); \
                   __builtin_amdgcn_s_barrier();
#define PH_CLOSE_VM2() __builtin_amdgcn_s_setprio(0); \
                   asm volatile("s_waitcnt vmcnt(2)" ::: "memory"); \
                   __builtin_amdgcn_sched_barrier(0); \
                   __builtin_amdgcn_s_barrier();
#define PH_CLOSE_VM5() __builtin_amdgcn_s_setprio(0); \
                   asm volatile("s_waitcnt vmcnt(5)" ::: "memory"); \
                   __builtin_amdgcn_sched_barrier(0); \
                   __builtin_amdgcn_s_barrier();

    bf16x8 af[8], bfA[4], bfB[4], bfC[4];

    STAGE_B(0, 0, 0); STAGE_B(0, 1, 0); STAGE_A(0, 0, 0); STAGE_A(0, 1, 0);
    STAGE_A(1, 0, 1); STAGE_A(1, 1, 1); STAGE_B(1, 0, 1);
    asm volatile("s_waitcnt vmcnt(5)" ::: "memory");
    __builtin_amdgcn_sched_barrier(0);
    __builtin_amdgcn_s_barrier();

    for (int it = 0; it < 8; ++it) {
        const int t1 = 2 * it + 1;
        const int c2 = (2 * it + 2 < 16) ? 2 * it + 2 : 14;
        const int c3 = (2 * it + 3 < 16) ? 2 * it + 3 : 15;
        const int b2 = c2 & 1, b3 = c3 & 1;

        LDA(af, 0); LDB(bfA, 0, 0);
        STAGE_B(1, 1, t1);
        PH_OPEN(); MF(af, bfA, 0); PH_CLOSE();
        LDB(bfB, 0, 1);
        STAGE_A(b2, 0, c2); STAGE_A(b2, 1, c2);
        PH_OPEN(); MF(af, bfB, 1); PH_CLOSE();
        LDB(bfC, 0, 2);
        PH_OPEN(); MF(af, bfC, 2); PH_CLOSE_VM2();

        LDA(af, 1); LDB(bfA, 1, 0);
        STAGE_B(b2, 0, c2);
        PH_OPEN(); MF(af, bfA, 0); PH_CLOSE();
        LDB(bfB, 1, 1);
        STAGE_B(b2, 1, c2); STAGE_A(b3, 0, c3); STAGE_A(b3, 1, c3);
        PH_OPEN(); MF(af, bfB, 1); PH_CLOSE();
        LDB(bfC, 1, 2);
        STAGE_B(b3, 0, c3);
        PH_OPEN(); MF(af, bfC, 2); PH_CLOSE_VM5();
    }
#undef PH_OPEN
#undef PH_CLOSE
#undef PH_CLOSE_VM2
#undef PH_CLOSE_VM5

    #pragma unroll
    for (int m = 0; m < 4; m++) {
        const int rowb = m0 + wr * 64 + m * 16 + lg * 4;
        const int b = rowb >> 11, t0r = rowb & 2047;
        #pragma unroll
        for (int nf = 0; nf < 6; nf++) {
            const int col = n0 + wc * 96 + nf * 16 + lr;
            const int proj = col >> 10;
            const int colL = col & 1023;
            const int hh = colL >> 6, dd = colL & 63;
            if (proj < 2) {
                const float* bias = (proj == 0) ? biasq : biask;
                const float bsc = (proj == 0) ? 0.125f * 1.4426950408889634f : 1.0f;
                __hip_bfloat16* dst = (proj == 0) ? oq : okk;
                #pragma unroll
                for (int rr = 0; rr < 4; rr++) {
                    const int row = rowb + rr;
                    float val = (acc[m][nf][rr] + bias[colL]) * bsc;
                    dst[(((size_t)(b * NH + hh)) * T_SEQ + (row & 2047)) * DHD + dd] = __float2bfloat16(val);
                }
            } else {
                const float bv = biasv[colL];
                union { __hip_bfloat16 h[4]; u32x2 u; } p;
                #pragma unroll
                for (int rr = 0; rr < 4; rr++)
                    p.h[rr] = __float2bfloat16(acc[m][nf][rr] + bv);
                *(u32x2*)&ovt[(((size_t)(b * NH + hh)) * DHD + dd) * T_SEQ + t0r] = p.u;
            }
        }
    }
}

// ---------------- proj GEMM v2: 128x128 tile, BK=64, 4-phase counted-vmcnt, 256 blocks ----------------
__global__ __launch_bounds__(512) void gemm_proj2(const __hip_bfloat16* __restrict__ A,
                                                  const __hip_bfloat16* __restrict__ Bw,
                                                  const float* __restrict__ biasp,
                                                  float* __restrict__ outf) {
    __shared__ __align__(16) char lds[65536]; // A: 2buf x 2half x 8KB @0; B same @32768

    const int wg = ((int)blockIdx.x & 7) * 32 + ((int)blockIdx.x >> 3); // bijective, 256%8==0
    const int m0 = (wg & 31) * 128;
    const int n0 = (wg >> 5) * 128;

    const int tid = threadIdx.x;
    const int w = tid >> 6, l = tid & 63;
    const int wr = w >> 2, wc = w & 3;
    const int lg = l >> 4, lr = l & 15;

    const int sr0 = tid >> 3;
    const int sc0 = (tid & 7) * 16;
    const int gc0 = sc0 ^ ((sr0 & 7) << 4);
    const size_t goff = (size_t)sr0 * 2048 + gc0;

    const char* Ag = (const char*)A + (size_t)m0 * 2048;
    const char* Bg = (const char*)Bw + (size_t)n0 * 2048;

    auto STAGE_A = [&](int buf, int half, int kt) {
        const char* g = Ag + (size_t)(half * 64) * 2048 + kt * 128 + goff;
        char* d = lds + (buf * 2 + half) * 8192 + w * 1024;
        async_copy16(d, g);
    };
    auto STAGE_B = [&](int buf, int half, int kt) {
        const char* g = Bg + (size_t)(half * 64) * 2048 + kt * 128 + goff;
        char* d = lds + 32768 + (buf * 2 + half) * 8192 + w * 1024;
        async_copy16(d, g);
    };

    const int sw = (lr & 7) << 4;
    auto LDA = [&](bf16x8* af, int buf) {
        const char* base = lds + (buf * 2 + wr) * 8192;
        #pragma unroll
        for (int m = 0; m < 4; m++) {
            const int r = m * 16 + lr;
            #pragma unroll
            for (int kk = 0; kk < 2; kk++)
                af[m * 2 + kk] = *(const bf16x8*)(base + r * 128 + ((kk * 64 + lg * 16) ^ sw));
        }
    };
    auto LDB = [&](bf16x8* bfv, int buf, int n) {
        const char* base = lds + 32768 + (buf * 2 + (wc >> 1)) * 8192;
        const int r = (wc & 1) * 32 + n * 16 + lr;
        #pragma unroll
        for (int kk = 0; kk < 2; kk++)
            bfv[kk] = *(const bf16x8*)(base + r * 128 + ((kk * 64 + lg * 16) ^ sw));
    };

    f32x4 acc[4][2] = {};
    auto MF = [&](const bf16x8* af, const bf16x8* bfv, int n) {
        #pragma unroll
        for (int m = 0; m < 4; m++)
            #pragma unroll
            for (int kk = 0; kk < 2; kk++)
                acc[m][n] = __builtin_amdgcn_mfma_f32_16x16x32_bf16(
                    af[m * 2 + kk], bfv[kk], acc[m][n], 0, 0, 0);
    };

#define PH_OPEN()  __builtin_amdgcn_sched_barrier(0); \
                   __builtin_amdgcn_s_barrier(); \
                   asm volatile("s_waitcnt lgkmcnt(0)" ::: "memory"); \
                   __builtin_amdgcn_sched_barrier(0); \
                   __builtin_amdgcn_s_setprio(1);
#define PH_CLOSE() __builtin_amdgcn_s_setprio(0); \
                   __builtin_amdgcn_sched_barrier(0); \
                   __builtin_amdgcn_s_barrier();
#define PH_CLOSE_VM2() __builtin_amdgcn_s_setprio(0); \
                   asm volatile("s_waitcnt vmcnt(2)" ::: "memory"); \
                   __builtin_amdgcn_sched_barrier(0); \
                   __builtin_amdgcn_s_barrier();

    bf16x8 af[8], bf0[2], bf1[2];

    STAGE_B(0, 0, 0); STAGE_B(0, 1, 0); STAGE_A(0, 0, 0); STAGE_A(0, 1, 0);
    STAGE_A(1, 0, 1); STAGE_A(1, 1, 1);
    asm volatile("s_waitcnt vmcnt(2)" ::: "memory");
    __builtin_amdgcn_sched_barrier(0);
    __builtin_amdgcn_s_barrier();

    for (int it = 0; it < 8; ++it) {
        const int t1 = 2 * it + 1;
        const int c2 = (2 * it + 2 < 16) ? 2 * it + 2 : 14;
        const int c3 = (2 * it + 3 < 16) ? 2 * it + 3 : 15;
        const int b2 = c2 & 1, b3 = c3 & 1;

        LDA(af, 0); LDB(bf0, 0, 0);
        STAGE_B(1, 0, t1); STAGE_B(1, 1, t1);
        PH_OPEN(); MF(af, bf0, 0); PH_CLOSE();
        LDB(bf1, 0, 1);
        STAGE_A(b2, 0, c2); STAGE_A(b2, 1, c2);
        PH_OPEN(); MF(af, bf1, 1); PH_CLOSE_VM2();

        LDA(af, 1); LDB(bf0, 1, 0);
        STAGE_B(b2, 0, c2); STAGE_B(b2, 1, c2);
        PH_OPEN(); MF(af, bf0, 0); PH_CLOSE();
        LDB(bf1, 1, 1);
        STAGE_A(b3, 0, c3); STAGE_A(b3, 1, c3);
        PH_OPEN(); MF(af, bf1, 1); PH_CLOSE_VM2();
    }
#undef PH_OPEN
#undef PH_CLOSE
#undef PH_CLOSE_VM2

    #pragma unroll
    for (int m = 0; m < 4; m++)
        #pragma unroll
        for (int n = 0; n < 2; n++)
            #pragma unroll
            for (int r = 0; r < 4; r++) {
                int row = m0 + wr * 64 + m * 16 + lg * 4 + r;
                int col = n0 + wc * 32 + n * 16 + lr;
                outf[(size_t)row * C_DIM + col] = acc[m][n][r] + biasp[col];
            }
}

// ---------------- flash attention v12: attn8 skeleton + 136B-row LDS (2-way banks, 8B ops) ----------------
__global__ __launch_bounds__(256) void attn12(const __hip_bfloat16* __restrict__ Q,
                                              const __hip_bfloat16* __restrict__ K,
                                              const __hip_bfloat16* __restrict__ Vt,
                                              __hip_bfloat16* __restrict__ Y) {
    const int bid = blockIdx.x;
    const int xcd = bid & 7, slot = bid >> 3;
    const int head = xcd * 4 + (slot & 3);
    const int qblk = slot >> 2;

    const int tid = threadIdx.x;
    const int w = tid >> 6, l = tid & 63;
    const int lq = l & 31, hi = l >> 5;
    const int q0 = qblk * 128 + w * 32;

    // K bufs @ buf*8704; V bufs @ 26112 + buf*8704; bc @ 52224  (total 52736 B)
    __shared__ __align__(16) char ldsa[52736];
    float* bc = (float*)(ldsa + 52224);

    const char* Kb = (const char*)(K + (size_t)head * T_SEQ * DHD);
    const char* Vb = (const char*)(Vt + (size_t)head * DHD * T_SEQ);

    bf16x8 qf[4];
    {
        const char* qrow = (const char*)(Q + ((size_t)head * T_SEQ + q0 + lq) * DHD);
        #pragma unroll
        for (int t = 0; t < 4; t++) qf[t] = *(const bf16x8*)(qrow + t * 32 + hi * 16);
    }

    f32x16 yacc[2] = {};
    float ls0 = 0.f, ls1 = 0.f, ls2 = 0.f, ls3 = 0.f;

    // staging: thread covers 2x16B linear of the 8KB tile; LDS addr padded to 136B rows
    const int o0 = (2 * w) * 1024 + l * 16;
    const int o1 = o0 + 1024;
    const int r0 = o0 >> 7, c0b = o0 & 127;
    const int r1 = o1 >> 7, c1b = o1 & 127;
    const int wadr0 = r0 * ROWB + c0b;   // 8B-aligned
    const int wadr1 = r1 * ROWB + c1b;
    const char* vsrc0 = Vb + (size_t)r0 * (T_SEQ * 2) + c0b;
    const char* vsrc1 = Vb + (size_t)r1 * (T_SEQ * 2) + c1b;

    float4 kreg0, kreg1, vreg0, vreg1;
    auto stage_load = [&](int tile) {
        const char* kb2 = Kb + (size_t)tile * 8192;
        kreg0 = *(const float4*)(kb2 + o0);
        kreg1 = *(const float4*)(kb2 + o1);
        vreg0 = *(const float4*)(vsrc0 + (size_t)tile * 128);
        vreg1 = *(const float4*)(vsrc1 + (size_t)tile * 128);
    };
    auto stage_write = [&](int buf) {
        char* ks = ldsa + buf * 8704;
        char* vs = ldsa + 26112 + buf * 8704;
        *(float2*)(ks + wadr0)     = make_float2(kreg0.x, kreg0.y);
        *(float2*)(ks + wadr0 + 8) = make_float2(kreg0.z, kreg0.w);
        *(float2*)(ks + wadr1)     = make_float2(kreg1.x, kreg1.y);
        *(float2*)(ks + wadr1 + 8) = make_float2(kreg1.z, kreg1.w);
        *(float2*)(vs + wadr0)     = make_float2(vreg0.x, vreg0.y);
        *(float2*)(vs + wadr0 + 8) = make_float2(vreg0.z, vreg0.w);
        *(float2*)(vs + wadr1)     = make_float2(vreg1.x, vreg1.y);
        *(float2*)(vs + wadr1 + 8) = make_float2(vreg1.z, vreg1.w);
    };

    auto qk = [&](int buf, f32x16& s0h, f32x16& s1h) {
        s0h = f32x16{}; s1h = f32x16{};
        const char* base0 = ldsa + buf * 8704 + lq * ROWB + hi * 16;
        const char* base1 = base0 + 32 * ROWB;
        __builtin_amdgcn_s_setprio(1);
        #pragma unroll
        for (int t = 0; t < 4; t++) {
            bf16x8 kf0 = ld_frag8(base0 + t * 32);
            s0h = __builtin_amdgcn_mfma_f32_32x32x16_bf16(kf0, qf[t], s0h, 0, 0, 0);
        }
        #pragma unroll
        for (int t = 0; t < 4; t++) {
            bf16x8 kf1 = ld_frag8(base1 + t * 32);
            s1h = __builtin_amdgcn_mfma_f32_32x32x16_bf16(kf1, qf[t], s1h, 0, 0, 0);
        }
        __builtin_amdgcn_s_setprio(0);
    };

    auto sm_exp = [&](f32x16& a, f32x16& b) {
        #pragma unroll
        for (int r = 0; r < 16; r += 4) {
            a[r + 0] = exp2_hw(a[r + 0]); a[r + 1] = exp2_hw(a[r + 1]);
            a[r + 2] = exp2_hw(a[r + 2]); a[r + 3] = exp2_hw(a[r + 3]);
            b[r + 0] = exp2_hw(b[r + 0]); b[r + 1] = exp2_hw(b[r + 1]);
            b[r + 2] = exp2_hw(b[r + 2]); b[r + 3] = exp2_hw(b[r + 3]);
            ls0 += a[r + 0] + b[r + 0];
            ls1 += a[r + 1] + b[r + 1];
            ls2 += a[r + 2] + b[r + 2];
            ls3 += a[r + 3] + b[r + 3];
        }
    };

    auto pv = [&](int buf, const f32x16& a, const f32x16& b) {
        unsigned pw0[8], pw1[8];
        #pragma unroll
        for (int M = 0; M < 4; M++) {
            const int u = M * 4;
            pw0[M] = cvtpk_bf16(a[u + 0], a[u + 1]);
            pw1[M] = cvtpk_bf16(a[u + 2], a[u + 3]);
            pw0[M + 4] = cvtpk_bf16(b[u + 0], b[u + 1]);
            pw1[M + 4] = cvtpk_bf16(b[u + 2], b[u + 3]);
        }
        const char* vb0 = ldsa + 26112 + buf * 8704 + lq * ROWB + hi * 16;
        __builtin_amdgcn_s_setprio(1);
        #pragma unroll
        for (int t = 0; t < 4; t++) {
            u32x2 s0p = __builtin_amdgcn_permlane32_swap(pw0[2 * t], pw0[2 * t + 1], false, false);
            u32x2 s1p = __builtin_amdgcn_permlane32_swap(pw1[2 * t], pw1[2 * t + 1], false, false);
            union { unsigned u[4]; bf16x8 v; } af;
            af.u[0] = s0p.x; af.u[1] = s1p.x; af.u[2] = s0p.y; af.u[3] = s1p.y;
            #pragma unroll
            for (int dh = 0; dh < 2; dh++) {
                bf16x8 vf = ld_frag8(vb0 + dh * (32 * ROWB) + t * 32);
                yacc[dh] = __builtin_amdgcn_mfma_f32_32x32x16_bf16(af.v, vf, yacc[dh], 0, 0, 0);
            }
        }
        __builtin_amdgcn_s_setprio(0);
    };

    // prologue: tiles 0,1 in bufs 0,1; tile 2 in regs; S(0) computed
    f32x16 sA0, sA1, sB0, sB1;
    stage_load(0); stage_write(0);
    stage_load(1); stage_write(1);
    stage_load(2);
    __syncthreads();
    qk(0, sA0, sA1);

    // attn8's proven raw-barrier pipeline
    for (int t = 0; t < 32; t += 2) {
        qk((t + 1) % 3, sB0, sB1);
        if (t + 2 < 32) {
            asm volatile("s_waitcnt vmcnt(0)" ::: "memory");
            stage_write((t + 2) % 3);
            if (t + 3 < 32) stage_load(t + 3);
        }
        sm_exp(sA0, sA1);
        pv(t % 3, sA0, sA1);
        asm volatile("s_waitcnt lgkmcnt(0)" ::: "memory");
        __builtin_amdgcn_s_barrier();
        __builtin_amdgcn_sched_barrier(0);

        const int t1 = t + 1;
        if (t1 + 1 < 32) qk((t1 + 1) % 3, sA0, sA1);
        if (t1 + 2 < 32) {
            asm volatile("s_waitcnt vmcnt(0)" ::: "memory");
            stage_write((t1 + 2) % 3);
            if (t1 + 3 < 32) stage_load(t1 + 3);
        }
        sm_exp(sB0, sB1);
        pv(t1 % 3, sB0, sB1);
        asm volatile("s_waitcnt lgkmcnt(0)" ::: "memory");
        __builtin_amdgcn_s_barrier();
        __builtin_amdgcn_sched_barrier(0);
    }

    float lsum = (ls0 + ls1) + (ls2 + ls3);
    lsum += __shfl_xor(lsum, 32);
    float inv = 1.0f / lsum;
    if (hi == 0) bc[w * 32 + lq] = inv;
    asm volatile("s_waitcnt lgkmcnt(0)" ::: "memory");
    __builtin_amdgcn_sched_barrier(0);

    const int b = head >> 4, h16 = head & 15;
    const size_t rowbase = (size_t)b * T_SEQ + q0;
    #pragma unroll
    for (int r = 0; r < 16; r++) {
        const int crow = (r & 3) + 8 * (r >> 2) + 4 * hi;
        const float iv = bc[w * 32 + crow];
        const size_t row = rowbase + crow;
        Y[row * C_DIM + h16 * DHD + lq]      = __float2bfloat16(yacc[0][r] * iv);
        Y[row * C_DIM + h16 * DHD + 32 + lq] = __float2bfloat16(yacc[1][r] * iv);
    }
}

// ---------------- launch ----------------
extern "C" void kernel_launch(void* const* d_in, const int* in_sizes, int n_in,
                              void* d_out, int out_size, void* d_ws, size_t ws_size,
                              hipStream_t stream) {
    (void)in_sizes; (void)n_in; (void)out_size; (void)ws_size;
    const float* x  = (const float*)d_in[0];
    const float* Wq = (const float*)d_in[1];
    const float* bq = (const float*)d_in[2];
    const float* Wk = (const float*)d_in[3];
    const float* bk = (const float*)d_in[4];
    const float* Wv = (const float*)d_in[5];
    const float* bv = (const float*)d_in[6];
    const float* Wp = (const float*)d_in[7];
    const float* bp = (const float*)d_in[8];
    float* out = (float*)d_out;

    char* ws = (char*)d_ws;
    const size_t MC = (size_t)4096 * C_DIM;
    const size_t CC = (size_t)C_DIM * C_DIM;
    __hip_bfloat16* xb  = (__hip_bfloat16*)ws;  ws += MC * 2;
    __hip_bfloat16* wf  = (__hip_bfloat16*)ws;  ws += 3 * CC * 2;   // Wq|Wk|Wv fused
    __hip_bfloat16* wpb = (__hip_bfloat16*)ws;  ws += CC * 2;
    __hip_bfloat16* qb  = (__hip_bfloat16*)ws;  ws += MC * 2;
    __hip_bfloat16* kb  = (__hip_bfloat16*)ws;  ws += MC * 2;
    __hip_bfloat16* vtb = (__hip_bfloat16*)ws;  ws += MC * 2;
    __hip_bfloat16* yb  = (__hip_bfloat16*)ws;  ws += MC * 2;

    cvt_all<<<8192, 256, 0, stream>>>(x, Wq, Wk, Wv, Wp, xb, wf, wpb);

    gemm_qkv<<<256, 512, 0, stream>>>(xb, wf, bq, bk, bv, qb, kb, vtb);

    attn12<<<512, 256, 0, stream>>>(qb, kb, vtb, yb);

    gemm_proj2<<<256, 512, 0, stream>>>(yb, wpb, bp, out);
}